// Round 7
// baseline (712.470 us; speedup 1.0000x reference)
//
#include <hip/hip_runtime.h>
#include <math.h>

#define B_ 8
#define S_ 512
#define D_ 512
#define WIDTH_ 16
#define NSEQ 544                 // S + 2*WIDTH
#define MROWS 4352               // B*NSEQ
#define MOUT 4096                // B*S
#define OUTHALF 4194304          // B*S*2D floats per output tensor
#define NBLK 512                 // persistent grid (resource-guaranteed co-resident)

typedef _Float16 half8 __attribute__((ext_vector_type(8)));
typedef _Float16 half4 __attribute__((ext_vector_type(4)));
typedef float floatx4 __attribute__((ext_vector_type(4)));

// async global->LDS, 16B per lane, dest = wave-uniform base + lane*16
#define GLD16(g, l) __builtin_amdgcn_global_load_lds(                          \
    (const __attribute__((address_space(1))) void*)(g),                        \
    (__attribute__((address_space(3))) void*)(l), 16, 0, 0)

__device__ __forceinline__ float sigmoidf_(float x) {
    return 1.f / (1.f + __expf(-x));
}

struct Args {
    const float *inputs, *left_pad, *right_pad;
    const float *l_Wqkv, *l_bqkv, *l_Wo, *l_bo;
    const float *r_Wqkv, *r_bqkv, *r_Wo, *r_bo;
    const float *lhw_W, *lhw_b, *rhw_W, *rhw_b;
    _Float16 *padX16, *w16;
    _Float16 *lqkv16, *rqkv16, *lWo16, *rWo16, *lhw16, *rhw16;
    _Float16 *qkv16, *att16, *x16a, *x16b;
    float *out_all, *out_last;
    int *bar;                     // [cnt, gen] zeroed by memset node
};

// ---- software grid barrier (sense-reversing, agent-scope atomics) ----
__device__ __forceinline__ void gsync(int* bar, int tid) {
    __syncthreads();
    if (tid == 0) {
        int* cnt = bar;
        int* gen = bar + 1;
        const int g = __hip_atomic_load(gen, __ATOMIC_RELAXED, __HIP_MEMORY_SCOPE_AGENT);
        const int prev = __hip_atomic_fetch_add(cnt, 1, __ATOMIC_ACQ_REL, __HIP_MEMORY_SCOPE_AGENT);
        if (prev == NBLK - 1) {
            __hip_atomic_store(cnt, 0, __ATOMIC_RELAXED, __HIP_MEMORY_SCOPE_AGENT);
            __hip_atomic_fetch_add(gen, 1, __ATOMIC_RELEASE, __HIP_MEMORY_SCOPE_AGENT);
        } else {
            while (__hip_atomic_load(gen, __ATOMIC_ACQUIRE, __HIP_MEMORY_SCOPE_AGENT) == g)
                __builtin_amdgcn_s_sleep(8);
        }
    }
    __syncthreads();
}

// ---------------- phase 0: weight cvt + pad concat ----------------
__device__ __forceinline__ void prep_phase(const Args& a, int pb, int tid) {
    for (int gb = pb; gb < 6272; gb += NBLK) {
        if (gb < 4096) {
            int idx = gb * 256 + tid;
            const float* src; int off;
            if      (idx < 196608) { src = a.l_Wqkv; off = idx; }
            else if (idx < 393216) { src = a.r_Wqkv; off = idx - 196608; }
            else if (idx < 458752) { src = a.l_Wo;   off = idx - 393216; }
            else if (idx < 524288) { src = a.r_Wo;   off = idx - 458752; }
            else if (idx < 786432) { src = a.lhw_W;  off = idx - 524288; }
            else                   { src = a.rhw_W;  off = idx - 786432; }
            const float4 v = ((const float4*)src)[off];
            half4 h = { (_Float16)v.x, (_Float16)v.y, (_Float16)v.z, (_Float16)v.w };
            ((half4*)a.w16)[idx] = h;
        } else {
            int idx = (gb - 4096) * 256 + tid;   // MROWS*128 total
            const int c4 = idx & 127;
            const int t  = idx >> 7;
            const int n = t % NSEQ;
            const int b = t / NSEQ;
            const float* src;
            if (n < WIDTH_)            src = a.left_pad + n * 512;
            else if (n < WIDTH_ + S_)  src = a.inputs + ((size_t)(b * S_ + n - WIDTH_)) * 512;
            else                       src = a.right_pad + (n - WIDTH_ - S_) * 512;
            const float4 v = *(const float4*)(src + c4 * 4);
            half4 h = { (_Float16)v.x, (_Float16)v.y, (_Float16)v.z, (_Float16)v.w };
            *(half4*)&a.padX16[(size_t)t * 512 + c4 * 4] = h;
        }
    }
}

// ---------------- phase 1: QKV GEMM 128x128 tiles ----------------
__device__ __forceinline__ void qkv_phase(const Args& a, int pb, int tid,
                                          _Float16* As, _Float16* Bs) {
    const int lda = 512, ldb = 512, ldc = 1536, K = 512;
    const int wave = tid >> 6;
    const int lane = tid & 63;
    for (int job = pb; job < 816; job += NBLK) {
        const int z   = job / 408;
        const int rem = job % 408;
        const int bm  = (rem / 12) * 128;
        const int bn  = (rem % 12) * 128;
        const _Float16* A = a.padX16;
        const _Float16* B = z ? a.rqkv16 : a.lqkv16;
        const float* bias = z ? a.r_bqkv : a.l_bqkv;
        _Float16* C = a.qkv16 + (size_t)z * MROWS * 1536;
        const int wm = (wave & 1) * 64;
        const int wn = (wave >> 1) * 64;

        const int inst = wave * 2;
        const int r0 = inst * 16 + (lane >> 2);
        const int kf = (lane & 3) * 8;

        const _Float16* Ag0 = A + (size_t)(bm + r0) * lda + kf;
        const _Float16* Ag1 = Ag0 + (size_t)16 * lda;
        const _Float16* Bg0 = B + (size_t)(bn + r0) * ldb + kf;
        const _Float16* Bg1 = Bg0 + (size_t)16 * ldb;
        _Float16* As0 = &As[inst * 512];
        _Float16* As1 = As0 + 512;
        _Float16* Bs0 = &Bs[inst * 512];
        _Float16* Bs1 = Bs0 + 512;

        const int fr = lane & 15;
        const int fq = (lane >> 4) * 8;

        floatx4 acc[4][4] = {};

        for (int k0 = 0; k0 < K; k0 += 32) {
            GLD16(Ag0, As0); GLD16(Ag1, As1);
            GLD16(Bg0, Bs0); GLD16(Bg1, Bs1);
            Ag0 += 32; Ag1 += 32; Bg0 += 32; Bg1 += 32;
            __syncthreads();
            half8 af[4], bf[4];
#pragma unroll
            for (int s = 0; s < 4; s++) {
                af[s] = *(const half8*)&As[(wm + s * 16 + fr) * 32 + fq];
                bf[s] = *(const half8*)&Bs[(wn + s * 16 + fr) * 32 + fq];
            }
#pragma unroll
            for (int i = 0; i < 4; i++)
#pragma unroll
                for (int j = 0; j < 4; j++)
                    acc[i][j] = __builtin_amdgcn_mfma_f32_16x16x32_f16(
                        af[i], bf[j], acc[i][j], 0, 0, 0);
            __syncthreads();
        }

        const int rq = (lane >> 4) * 4;
        const int cc = lane & 15;
#pragma unroll
        for (int i = 0; i < 4; i++) {
            const int rbase = bm + wm + i * 16 + rq;
#pragma unroll
            for (int j = 0; j < 4; j++) {
                const int col = bn + wn + j * 16 + cc;
                const float bv = bias[col];
#pragma unroll
                for (int r = 0; r < 4; r++)
                    C[(size_t)(rbase + r) * ldc + col] = (_Float16)(acc[i][j][r] + bv);
            }
        }
    }
}

// ---------------- phase 2: windowed attention ----------------
__device__ __forceinline__ void attn_phase(const Args& a, int pb, int tid) {
    for (int job = pb; job < 2176; job += NBLK) {
        const int dir = job / 1088;
        const int jx  = job % 1088;
        const int dlo = dir ? 0 : -(WIDTH_ + 1);
        const _Float16* qkv = a.qkv16 + (size_t)dir * MROWS * 1536;
        _Float16* att = a.att16 + (size_t)dir * MROWS * 512;
        const int t  = jx * 256 + tid;
        const int h  = t & 63;
        const int bi = t >> 6;
        const int i  = bi % NSEQ;
        const int b  = bi / NSEQ;
        const int j0 = i + dlo;
        const float scale = 0.35355339059327373f;  // 1/sqrt(8)

        const half8 q8 = *(const half8*)(qkv + (size_t)bi * 1536 + h * 8);
        float q[8];
#pragma unroll
        for (int d = 0; d < 8; d++) q[d] = (float)q8[d];

        float s[18];
        float mx = -1e30f;
#pragma unroll
        for (int jj = 0; jj < 18; jj++) {
            const int j = j0 + jj;
            const int jc = j < 0 ? 0 : (j > NSEQ - 1 ? NSEQ - 1 : j);
            const half8 k8 = *(const half8*)(qkv + (size_t)(b * NSEQ + jc) * 1536 + 512 + h * 8);
            float d = 0.f;
#pragma unroll
            for (int dd = 0; dd < 8; dd++) d = fmaf(q[dd], (float)k8[dd], d);
            s[jj] = (j == jc) ? d * scale : -1e30f;
            mx = fmaxf(mx, s[jj]);
        }
        float sum = 0.f;
#pragma unroll
        for (int jj = 0; jj < 18; jj++) { s[jj] = __expf(s[jj] - mx); sum += s[jj]; }
        const float inv = 1.f / sum;

        float o[8] = {};
#pragma unroll
        for (int jj = 0; jj < 18; jj++) {
            const int j = j0 + jj;
            const int jc = j < 0 ? 0 : (j > NSEQ - 1 ? NSEQ - 1 : j);
            const half8 v8 = *(const half8*)(qkv + (size_t)(b * NSEQ + jc) * 1536 + 1024 + h * 8);
            const float p = s[jj];
#pragma unroll
            for (int dd = 0; dd < 8; dd++) o[dd] = fmaf(p, (float)v8[dd], o[dd]);
        }
        half8 o16;
#pragma unroll
        for (int d = 0; d < 8; d++) o16[d] = (_Float16)(o[d] * inv);
        *(half8*)&att[(size_t)bi * 512 + h * 8] = o16;
    }
}

// ---------------- phase 3: Wo GEMM 64x128 + slice epilogue ----------------
__device__ __forceinline__ void wo_phase(const Args& a, int pb, int tid,
                                         _Float16* As, _Float16* Bs) {
    const int lda = 512, ldb = 512, K = 512;
    const int wave = tid >> 6;
    const int lane = tid & 63;
    for (int job = pb; job < 544; job += NBLK) {
        const int z   = job / 272;
        const int rem = job % 272;
        const int bm  = (rem / 4) * 64;
        const int bn  = (rem % 4) * 128;
        const _Float16* A = a.att16 + (size_t)z * MROWS * 512;
        const _Float16* B = z ? a.rWo16 : a.lWo16;
        const float* bias = z ? a.r_bo : a.l_bo;
        _Float16* x16 = a.x16a + (size_t)z * MOUT * 512;

        const int wm = (wave & 1) * 32;
        const int wn = (wave >> 1) * 64;

        const int rA = wave * 16 + (lane >> 2);
        const int rB = wave * 32 + (lane >> 2);
        const int kf = (lane & 3) * 8;

        const _Float16* Ag0 = A + (size_t)(bm + rA) * lda + kf;
        const _Float16* Bg0 = B + (size_t)(bn + rB) * ldb + kf;
        const _Float16* Bg1 = Bg0 + (size_t)16 * ldb;
        _Float16* As0 = &As[wave * 512];
        _Float16* Bs0 = &Bs[wave * 1024];
        _Float16* Bs1 = Bs0 + 512;

        const int fr = lane & 15;
        const int fq = (lane >> 4) * 8;

        floatx4 acc[2][4] = {};

        for (int k0 = 0; k0 < K; k0 += 32) {
            GLD16(Ag0, As0);
            GLD16(Bg0, Bs0); GLD16(Bg1, Bs1);
            Ag0 += 32; Bg0 += 32; Bg1 += 32;
            __syncthreads();
            half8 af[2], bf[4];
#pragma unroll
            for (int s = 0; s < 2; s++)
                af[s] = *(const half8*)&As[(wm + s * 16 + fr) * 32 + fq];
#pragma unroll
            for (int s = 0; s < 4; s++)
                bf[s] = *(const half8*)&Bs[(wn + s * 16 + fr) * 32 + fq];
#pragma unroll
            for (int i = 0; i < 2; i++)
#pragma unroll
                for (int j = 0; j < 4; j++)
                    acc[i][j] = __builtin_amdgcn_mfma_f32_16x16x32_f16(
                        af[i], bf[j], acc[i][j], 0, 0, 0);
            __syncthreads();
        }

        const int rq = (lane >> 4) * 4;
        const int cc = lane & 15;
#pragma unroll
        for (int i = 0; i < 2; i++) {
            const int rbase = bm + wm + i * 16 + rq;
#pragma unroll
            for (int r = 0; r < 4; r++) {
                const int row = rbase + r;
                const int b = row / NSEQ;
                const int s = row - b * NSEQ;
                if (s < WIDTH_ || s >= WIDTH_ + S_) continue;
                const int m = b * S_ + s - WIDTH_;
#pragma unroll
                for (int j = 0; j < 4; j++) {
                    const int col = bn + wn + j * 16 + cc;
                    x16[(size_t)m * 512 + col] = (_Float16)(acc[i][j][r] + bias[col]);
                }
            }
        }
    }
}

// ---------------- phases 4/5: highway GEMM 128x64 dual-N ----------------
__device__ __forceinline__ void hw_phase(const Args& a, int pb, int tid,
                                         _Float16* As, _Float16* Bn, _Float16* Bg,
                                         const _Float16* x16inbase,
                                         const _Float16* W0, const _Float16* W1,
                                         const float* b0, const float* b1,
                                         _Float16* x16outbase,
                                         float* outlastbase, float* outallbase) {
    const int lda = 512, ldb = 512, K = 512;
    const int wave = tid >> 6;
    const int lane = tid & 63;
    for (int job = pb; job < 512; job += NBLK) {
        const int z   = job / 256;
        const int rem = job % 256;
        const int bm  = (rem / 8) * 128;
        const int bn  = (rem % 8) * 64;
        const _Float16* A = x16inbase + (size_t)z * MOUT * 512;
        const _Float16* W = z ? W1 : W0;
        const float* bias = z ? b1 : b0;
        _Float16* x16out = x16outbase ? x16outbase + (size_t)z * MOUT * 512 : nullptr;

        const int wm = (wave & 1) * 64;
        const int wn = (wave >> 1) * 32;

        const int rA = wave * 32 + (lane >> 2);
        const int rB = wave * 16 + (lane >> 2);
        const int kf = (lane & 3) * 8;

        const _Float16* Ag0 = A + (size_t)(bm + rA) * lda + kf;
        const _Float16* Ag1 = Ag0 + (size_t)16 * lda;
        const _Float16* Bn0 = W + (size_t)(bn + rB) * ldb + kf;
        const _Float16* Bg0 = W + (size_t)(512 + bn + rB) * ldb + kf;
        _Float16* As0  = &As[wave * 1024];
        _Float16* As1  = As0 + 512;
        _Float16* Bns0 = &Bn[wave * 512];
        _Float16* Bgs0 = &Bg[wave * 512];

        const int fr = lane & 15;
        const int fq = (lane >> 4) * 8;

        floatx4 accn[4][2] = {};
        floatx4 accg[4][2] = {};

        for (int k0 = 0; k0 < K; k0 += 32) {
            GLD16(Ag0, As0); GLD16(Ag1, As1);
            GLD16(Bn0, Bns0);
            GLD16(Bg0, Bgs0);
            Ag0 += 32; Ag1 += 32; Bn0 += 32; Bg0 += 32;
            __syncthreads();
            half8 af[4], bnf[2], bgf[2];
#pragma unroll
            for (int s = 0; s < 4; s++)
                af[s] = *(const half8*)&As[(wm + s * 16 + fr) * 32 + fq];
#pragma unroll
            for (int s = 0; s < 2; s++) {
                bnf[s] = *(const half8*)&Bn[(wn + s * 16 + fr) * 32 + fq];
                bgf[s] = *(const half8*)&Bg[(wn + s * 16 + fr) * 32 + fq];
            }
#pragma unroll
            for (int i = 0; i < 4; i++)
#pragma unroll
                for (int j = 0; j < 2; j++) {
                    accn[i][j] = __builtin_amdgcn_mfma_f32_16x16x32_f16(
                        af[i], bnf[j], accn[i][j], 0, 0, 0);
                    accg[i][j] = __builtin_amdgcn_mfma_f32_16x16x32_f16(
                        af[i], bgf[j], accg[i][j], 0, 0, 0);
                }
            __syncthreads();
        }

        float* outlast = outlastbase ? outlastbase + z * 512 : nullptr;
        float* outall  = outallbase  ? outallbase  + z * 512 : nullptr;

        const int rq = (lane >> 4) * 4;
        const int cc = lane & 15;
#pragma unroll
        for (int i = 0; i < 4; i++) {
            const int rbase = bm + wm + i * 16 + rq;
#pragma unroll
            for (int j = 0; j < 2; j++) {
                const int col = bn + wn + j * 16 + cc;
                const float bnl = bias[col];
                const float bgt = bias[512 + col];
#pragma unroll
                for (int r = 0; r < 4; r++) {
                    const int row = rbase + r;
                    const float nl = fmaxf(accn[i][j][r] + bnl, 0.f);
                    const float g  = sigmoidf_(accg[i][j][r] + bgt);
                    const float xo = (float)A[(size_t)row * 512 + col];
                    const float v  = g * xo + (1.f - g) * nl;
                    if (x16out) {
                        x16out[(size_t)row * 512 + col] = (_Float16)v;
                    } else {
                        outlast[(size_t)row * 1024 + col] = v;
                        outall[(size_t)row * 1024 + col] = v;
                    }
                }
            }
        }
    }
}

// =================== persistent mega kernel (software grid barrier) ==========
__global__ void __launch_bounds__(256, 2) mega(Args a) {
    __shared__ _Float16 S[8192];   // 16 KB, carved per phase
    const int pb  = blockIdx.x;
    const int tid = threadIdx.x;

    prep_phase(a, pb, tid);
    gsync(a.bar, tid);
    qkv_phase(a, pb, tid, S, S + 4096);
    gsync(a.bar, tid);
    attn_phase(a, pb, tid);
    gsync(a.bar, tid);
    wo_phase(a, pb, tid, S, S + 2048);
    gsync(a.bar, tid);
    hw_phase(a, pb, tid, S, S + 4096, S + 6144,
             a.x16a, a.lhw16, a.rhw16, a.lhw_b, a.rhw_b,
             a.x16b, nullptr, nullptr);
    gsync(a.bar, tid);
    hw_phase(a, pb, tid, S, S + 4096, S + 6144,
             a.x16b, a.lhw16 + 524288, a.rhw16 + 524288,
             a.lhw_b + 1024, a.rhw_b + 1024,
             nullptr, a.out_last, a.out_all);
}

extern "C" void kernel_launch(void* const* d_in, const int* in_sizes, int n_in,
                              void* d_out, int out_size, void* d_ws, size_t ws_size,
                              hipStream_t stream) {
    float* out = (float*)d_out;
    _Float16* h = (_Float16*)d_ws;

    Args a;
    a.inputs    = (const float*)d_in[0];
    a.left_pad  = (const float*)d_in[1];
    a.right_pad = (const float*)d_in[2];
    a.l_Wqkv = (const float*)d_in[3];
    a.l_bqkv = (const float*)d_in[4];
    a.l_Wo   = (const float*)d_in[5];
    a.l_bo   = (const float*)d_in[6];
    a.r_Wqkv = (const float*)d_in[7];
    a.r_bqkv = (const float*)d_in[8];
    a.r_Wo   = (const float*)d_in[9];
    a.r_bo   = (const float*)d_in[10];
    a.lhw_W  = (const float*)d_in[11];
    a.lhw_b  = (const float*)d_in[12];
    a.rhw_W  = (const float*)d_in[13];
    a.rhw_b  = (const float*)d_in[14];

    a.padX16 = h;                    // 2,228,224 f16
    a.w16    = h + 2228224;          // 4,194,304 f16
    a.lqkv16 = a.w16;
    a.rqkv16 = a.w16 + 786432;
    a.lWo16  = a.w16 + 1572864;
    a.rWo16  = a.w16 + 1835008;
    a.lhw16  = a.w16 + 2097152;
    a.rhw16  = a.w16 + 3145728;
    a.qkv16  = h + 6422528;          // 13,369,344 (2 dirs)
    a.att16  = h + 19791872;         // 4,456,448  (2 dirs)
    a.x16a   = h + 24248320;         // 4,194,304  (2 dirs)
    a.x16b   = h + 28442624;         // 4,194,304  (2 dirs)
    a.out_all  = out;                // all_layers [1,B,S,2D]
    a.out_last = out + OUTHALF;      // last       [B,S,2D]

    // barrier state at the aligned tail of the workspace
    a.bar = (int*)((char*)d_ws + ((ws_size - 64) & ~(size_t)63));

    hipMemsetAsync(a.bar, 0, 8, stream);
    mega<<<dim3(NBLK), dim3(256), 0, stream>>>(a);
}

// Round 9
// 526.740 us; speedup vs baseline: 1.3526x; 1.3526x over previous
//
#include <hip/hip_runtime.h>
#include <math.h>

#define B_ 8
#define S_ 512
#define D_ 512
#define WIDTH_ 16
#define NSEQ 544                 // S + 2*WIDTH
#define MROWS 4352               // B*NSEQ
#define MOUT 4096                // B*S
#define OUTHALF 4194304          // B*S*2D floats per output tensor
#define NBLK 512                 // persistent grid; 2 blocks/CU PROVEN co-resident (R7)

typedef _Float16 half8 __attribute__((ext_vector_type(8)));
typedef _Float16 half4 __attribute__((ext_vector_type(4)));
typedef float floatx4 __attribute__((ext_vector_type(4)));

// async global->LDS, 16B per lane, dest = wave-uniform base + lane*16
#define GLD16(g, l) __builtin_amdgcn_global_load_lds(                          \
    (const __attribute__((address_space(1))) void*)(g),                        \
    (__attribute__((address_space(3))) void*)(l), 16, 0, 0)

__device__ __forceinline__ float sigmoidf_(float x) {
    return 1.f / (1.f + __expf(-x));
}

struct Args {
    const float *inputs, *left_pad, *right_pad;
    const float *l_Wqkv, *l_bqkv, *l_Wo, *l_bo;
    const float *r_Wqkv, *r_bqkv, *r_Wo, *r_bo;
    const float *lhw_W, *lhw_b, *rhw_W, *rhw_b;
    _Float16 *padX16, *w16;
    _Float16 *lqkv16, *rqkv16, *lWo16, *rWo16, *lhw16, *rhw16;
    _Float16 *qkv16, *att16, *x16a, *x16b;
    float *out_all, *out_last;
    int *bar;                     // [cnt, gen] zeroed by memset node
};

// ---- software grid barrier: sense-reversing. RELAXED polls (R7's
// ACQUIRE-per-poll emitted buffer_inv each iteration -> L1/L2 invalidate
// storm from ~half the grid spinning; theory for the 3.2x stall). One
// ACQUIRE after the flip is observed gives the happens-before edge;
// arrival RMW is ACQ_REL (flushes prior writes for cross-XCD visibility).
__device__ __forceinline__ void gsync(int* bar, int tid) {
    __syncthreads();
    if (tid == 0) {
        int* cnt = bar;
        int* gen = bar + 1;
        const int g = __hip_atomic_load(gen, __ATOMIC_RELAXED, __HIP_MEMORY_SCOPE_AGENT);
        const int prev = __hip_atomic_fetch_add(cnt, 1, __ATOMIC_ACQ_REL, __HIP_MEMORY_SCOPE_AGENT);
        if (prev == NBLK - 1) {
            __hip_atomic_store(cnt, 0, __ATOMIC_RELAXED, __HIP_MEMORY_SCOPE_AGENT);
            __hip_atomic_fetch_add(gen, 1, __ATOMIC_RELEASE, __HIP_MEMORY_SCOPE_AGENT);
        } else {
            while (__hip_atomic_load(gen, __ATOMIC_RELAXED, __HIP_MEMORY_SCOPE_AGENT) == g)
                __builtin_amdgcn_s_sleep(32);
            (void)__hip_atomic_load(gen, __ATOMIC_ACQUIRE, __HIP_MEMORY_SCOPE_AGENT);
        }
    }
    __syncthreads();
}

// ---------------- phase 0: weight cvt + pad concat ----------------
__device__ __forceinline__ void prep_phase(const Args& a, int pb, int tid) {
    for (int gb = pb; gb < 6272; gb += NBLK) {
        if (gb < 4096) {
            int idx = gb * 256 + tid;
            const float* src; int off;
            if      (idx < 196608) { src = a.l_Wqkv; off = idx; }
            else if (idx < 393216) { src = a.r_Wqkv; off = idx - 196608; }
            else if (idx < 458752) { src = a.l_Wo;   off = idx - 393216; }
            else if (idx < 524288) { src = a.r_Wo;   off = idx - 458752; }
            else if (idx < 786432) { src = a.lhw_W;  off = idx - 524288; }
            else                   { src = a.rhw_W;  off = idx - 786432; }
            const float4 v = ((const float4*)src)[off];
            half4 h = { (_Float16)v.x, (_Float16)v.y, (_Float16)v.z, (_Float16)v.w };
            ((half4*)a.w16)[idx] = h;
        } else {
            int idx = (gb - 4096) * 256 + tid;   // MROWS*128 total
            const int c4 = idx & 127;
            const int t  = idx >> 7;
            const int n = t % NSEQ;
            const int b = t / NSEQ;
            const float* src;
            if (n < WIDTH_)            src = a.left_pad + n * 512;
            else if (n < WIDTH_ + S_)  src = a.inputs + ((size_t)(b * S_ + n - WIDTH_)) * 512;
            else                       src = a.right_pad + (n - WIDTH_ - S_) * 512;
            const float4 v = *(const float4*)(src + c4 * 4);
            half4 h = { (_Float16)v.x, (_Float16)v.y, (_Float16)v.z, (_Float16)v.w };
            *(half4*)&a.padX16[(size_t)t * 512 + c4 * 4] = h;
        }
    }
}

// ---------------- phase 1: QKV GEMM 128x128 tiles ----------------
__device__ __forceinline__ void qkv_phase(const Args& a, int pb, int tid,
                                          _Float16* As, _Float16* Bs) {
    const int lda = 512, ldb = 512, ldc = 1536, K = 512;
    const int wave = tid >> 6;
    const int lane = tid & 63;
    for (int job = pb; job < 816; job += NBLK) {
        const int z   = job / 408;
        const int rem = job % 408;
        const int bm  = (rem / 12) * 128;
        const int bn  = (rem % 12) * 128;
        const _Float16* A = a.padX16;
        const _Float16* B = z ? a.rqkv16 : a.lqkv16;
        const float* bias = z ? a.r_bqkv : a.l_bqkv;
        _Float16* C = a.qkv16 + (size_t)z * MROWS * 1536;
        const int wm = (wave & 1) * 64;
        const int wn = (wave >> 1) * 64;

        const int inst = wave * 2;
        const int r0 = inst * 16 + (lane >> 2);
        const int kf = (lane & 3) * 8;

        const _Float16* Ag0 = A + (size_t)(bm + r0) * lda + kf;
        const _Float16* Ag1 = Ag0 + (size_t)16 * lda;
        const _Float16* Bg0 = B + (size_t)(bn + r0) * ldb + kf;
        const _Float16* Bg1 = Bg0 + (size_t)16 * ldb;
        _Float16* As0 = &As[inst * 512];
        _Float16* As1 = As0 + 512;
        _Float16* Bs0 = &Bs[inst * 512];
        _Float16* Bs1 = Bs0 + 512;

        const int fr = lane & 15;
        const int fq = (lane >> 4) * 8;

        floatx4 acc[4][4] = {};

        for (int k0 = 0; k0 < K; k0 += 32) {
            GLD16(Ag0, As0); GLD16(Ag1, As1);
            GLD16(Bg0, Bs0); GLD16(Bg1, Bs1);
            Ag0 += 32; Ag1 += 32; Bg0 += 32; Bg1 += 32;
            __syncthreads();
            half8 af[4], bf[4];
#pragma unroll
            for (int s = 0; s < 4; s++) {
                af[s] = *(const half8*)&As[(wm + s * 16 + fr) * 32 + fq];
                bf[s] = *(const half8*)&Bs[(wn + s * 16 + fr) * 32 + fq];
            }
#pragma unroll
            for (int i = 0; i < 4; i++)
#pragma unroll
                for (int j = 0; j < 4; j++)
                    acc[i][j] = __builtin_amdgcn_mfma_f32_16x16x32_f16(
                        af[i], bf[j], acc[i][j], 0, 0, 0);
            __syncthreads();
        }

        const int rq = (lane >> 4) * 4;
        const int cc = lane & 15;
#pragma unroll
        for (int i = 0; i < 4; i++) {
            const int rbase = bm + wm + i * 16 + rq;
#pragma unroll
            for (int j = 0; j < 4; j++) {
                const int col = bn + wn + j * 16 + cc;
                const float bv = bias[col];
#pragma unroll
                for (int r = 0; r < 4; r++)
                    C[(size_t)(rbase + r) * ldc + col] = (_Float16)(acc[i][j][r] + bv);
            }
        }
    }
}

// ---------------- phase 2: windowed attention ----------------
__device__ __forceinline__ void attn_phase(const Args& a, int pb, int tid) {
    for (int job = pb; job < 2176; job += NBLK) {
        const int dir = job / 1088;
        const int jx  = job % 1088;
        const int dlo = dir ? 0 : -(WIDTH_ + 1);
        const _Float16* qkv = a.qkv16 + (size_t)dir * MROWS * 1536;
        _Float16* att = a.att16 + (size_t)dir * MROWS * 512;
        const int t  = jx * 256 + tid;
        const int h  = t & 63;
        const int bi = t >> 6;
        const int i  = bi % NSEQ;
        const int b  = bi / NSEQ;
        const int j0 = i + dlo;
        const float scale = 0.35355339059327373f;  // 1/sqrt(8)

        const half8 q8 = *(const half8*)(qkv + (size_t)bi * 1536 + h * 8);
        float q[8];
#pragma unroll
        for (int d = 0; d < 8; d++) q[d] = (float)q8[d];

        float s[18];
        float mx = -1e30f;
#pragma unroll
        for (int jj = 0; jj < 18; jj++) {
            const int j = j0 + jj;
            const int jc = j < 0 ? 0 : (j > NSEQ - 1 ? NSEQ - 1 : j);
            const half8 k8 = *(const half8*)(qkv + (size_t)(b * NSEQ + jc) * 1536 + 512 + h * 8);
            float d = 0.f;
#pragma unroll
            for (int dd = 0; dd < 8; dd++) d = fmaf(q[dd], (float)k8[dd], d);
            s[jj] = (j == jc) ? d * scale : -1e30f;
            mx = fmaxf(mx, s[jj]);
        }
        float sum = 0.f;
#pragma unroll
        for (int jj = 0; jj < 18; jj++) { s[jj] = __expf(s[jj] - mx); sum += s[jj]; }
        const float inv = 1.f / sum;

        float o[8] = {};
#pragma unroll
        for (int jj = 0; jj < 18; jj++) {
            const int j = j0 + jj;
            const int jc = j < 0 ? 0 : (j > NSEQ - 1 ? NSEQ - 1 : j);
            const half8 v8 = *(const half8*)(qkv + (size_t)(b * NSEQ + jc) * 1536 + 1024 + h * 8);
            const float p = s[jj];
#pragma unroll
            for (int dd = 0; dd < 8; dd++) o[dd] = fmaf(p, (float)v8[dd], o[dd]);
        }
        half8 o16;
#pragma unroll
        for (int d = 0; d < 8; d++) o16[d] = (_Float16)(o[d] * inv);
        *(half8*)&att[(size_t)bi * 512 + h * 8] = o16;
    }
}

// ---------------- phase 3: Wo GEMM 64x128 + slice epilogue ----------------
__device__ __forceinline__ void wo_phase(const Args& a, int pb, int tid,
                                         _Float16* As, _Float16* Bs) {
    const int lda = 512, ldb = 512, K = 512;
    const int wave = tid >> 6;
    const int lane = tid & 63;
    for (int job = pb; job < 544; job += NBLK) {
        const int z   = job / 272;
        const int rem = job % 272;
        const int bm  = (rem / 4) * 64;
        const int bn  = (rem % 4) * 128;
        const _Float16* A = a.att16 + (size_t)z * MROWS * 512;
        const _Float16* B = z ? a.rWo16 : a.lWo16;
        const float* bias = z ? a.r_bo : a.l_bo;
        _Float16* x16 = a.x16a + (size_t)z * MOUT * 512;

        const int wm = (wave & 1) * 32;
        const int wn = (wave >> 1) * 64;

        const int rA = wave * 16 + (lane >> 2);
        const int rB = wave * 32 + (lane >> 2);
        const int kf = (lane & 3) * 8;

        const _Float16* Ag0 = A + (size_t)(bm + rA) * lda + kf;
        const _Float16* Bg0 = B + (size_t)(bn + rB) * ldb + kf;
        const _Float16* Bg1 = Bg0 + (size_t)16 * ldb;
        _Float16* As0 = &As[wave * 512];
        _Float16* Bs0 = &Bs[wave * 1024];
        _Float16* Bs1 = Bs0 + 512;

        const int fr = lane & 15;
        const int fq = (lane >> 4) * 8;

        floatx4 acc[2][4] = {};

        for (int k0 = 0; k0 < K; k0 += 32) {
            GLD16(Ag0, As0);
            GLD16(Bg0, Bs0); GLD16(Bg1, Bs1);
            Ag0 += 32; Bg0 += 32; Bg1 += 32;
            __syncthreads();
            half8 af[2], bf[4];
#pragma unroll
            for (int s = 0; s < 2; s++)
                af[s] = *(const half8*)&As[(wm + s * 16 + fr) * 32 + fq];
#pragma unroll
            for (int s = 0; s < 4; s++)
                bf[s] = *(const half8*)&Bs[(wn + s * 16 + fr) * 32 + fq];
#pragma unroll
            for (int i = 0; i < 2; i++)
#pragma unroll
                for (int j = 0; j < 4; j++)
                    acc[i][j] = __builtin_amdgcn_mfma_f32_16x16x32_f16(
                        af[i], bf[j], acc[i][j], 0, 0, 0);
            __syncthreads();
        }

        const int rq = (lane >> 4) * 4;
        const int cc = lane & 15;
#pragma unroll
        for (int i = 0; i < 2; i++) {
            const int rbase = bm + wm + i * 16 + rq;
#pragma unroll
            for (int r = 0; r < 4; r++) {
                const int row = rbase + r;
                const int b = row / NSEQ;
                const int s = row - b * NSEQ;
                if (s < WIDTH_ || s >= WIDTH_ + S_) continue;
                const int m = b * S_ + s - WIDTH_;
#pragma unroll
                for (int j = 0; j < 4; j++) {
                    const int col = bn + wn + j * 16 + cc;
                    x16[(size_t)m * 512 + col] = (_Float16)(acc[i][j][r] + bias[col]);
                }
            }
        }
    }
}

// ---------------- phases 4/5: highway GEMM 128x64 dual-N ----------------
__device__ __forceinline__ void hw_phase(const Args& a, int pb, int tid,
                                         _Float16* As, _Float16* Bn, _Float16* Bg,
                                         const _Float16* x16inbase,
                                         const _Float16* W0, const _Float16* W1,
                                         const float* b0, const float* b1,
                                         _Float16* x16outbase,
                                         float* outlastbase, float* outallbase) {
    const int lda = 512, ldb = 512, K = 512;
    const int wave = tid >> 6;
    const int lane = tid & 63;
    for (int job = pb; job < 512; job += NBLK) {
        const int z   = job / 256;
        const int rem = job % 256;
        const int bm  = (rem / 8) * 128;
        const int bn  = (rem % 8) * 64;
        const _Float16* A = x16inbase + (size_t)z * MOUT * 512;
        const _Float16* W = z ? W1 : W0;
        const float* bias = z ? b1 : b0;
        _Float16* x16out = x16outbase ? x16outbase + (size_t)z * MOUT * 512 : nullptr;

        const int wm = (wave & 1) * 64;
        const int wn = (wave >> 1) * 32;

        const int rA = wave * 32 + (lane >> 2);
        const int rB = wave * 16 + (lane >> 2);
        const int kf = (lane & 3) * 8;

        const _Float16* Ag0 = A + (size_t)(bm + rA) * lda + kf;
        const _Float16* Ag1 = Ag0 + (size_t)16 * lda;
        const _Float16* Bn0 = W + (size_t)(bn + rB) * ldb + kf;
        const _Float16* Bg0 = W + (size_t)(512 + bn + rB) * ldb + kf;
        _Float16* As0  = &As[wave * 1024];
        _Float16* As1  = As0 + 512;
        _Float16* Bns0 = &Bn[wave * 512];
        _Float16* Bgs0 = &Bg[wave * 512];

        const int fr = lane & 15;
        const int fq = (lane >> 4) * 8;

        floatx4 accn[4][2] = {};
        floatx4 accg[4][2] = {};

        for (int k0 = 0; k0 < K; k0 += 32) {
            GLD16(Ag0, As0); GLD16(Ag1, As1);
            GLD16(Bn0, Bns0);
            GLD16(Bg0, Bgs0);
            Ag0 += 32; Ag1 += 32; Bn0 += 32; Bg0 += 32;
            __syncthreads();
            half8 af[4], bnf[2], bgf[2];
#pragma unroll
            for (int s = 0; s < 4; s++)
                af[s] = *(const half8*)&As[(wm + s * 16 + fr) * 32 + fq];
#pragma unroll
            for (int s = 0; s < 2; s++) {
                bnf[s] = *(const half8*)&Bn[(wn + s * 16 + fr) * 32 + fq];
                bgf[s] = *(const half8*)&Bg[(wn + s * 16 + fr) * 32 + fq];
            }
#pragma unroll
            for (int i = 0; i < 4; i++)
#pragma unroll
                for (int j = 0; j < 2; j++) {
                    accn[i][j] = __builtin_amdgcn_mfma_f32_16x16x32_f16(
                        af[i], bnf[j], accn[i][j], 0, 0, 0);
                    accg[i][j] = __builtin_amdgcn_mfma_f32_16x16x32_f16(
                        af[i], bgf[j], accg[i][j], 0, 0, 0);
                }
            __syncthreads();
        }

        float* outlast = outlastbase ? outlastbase + z * 512 : nullptr;
        float* outall  = outallbase  ? outallbase  + z * 512 : nullptr;

        const int rq = (lane >> 4) * 4;
        const int cc = lane & 15;
#pragma unroll
        for (int i = 0; i < 4; i++) {
            const int rbase = bm + wm + i * 16 + rq;
#pragma unroll
            for (int j = 0; j < 2; j++) {
                const int col = bn + wn + j * 16 + cc;
                const float bnl = bias[col];
                const float bgt = bias[512 + col];
#pragma unroll
                for (int r = 0; r < 4; r++) {
                    const int row = rbase + r;
                    const float nl = fmaxf(accn[i][j][r] + bnl, 0.f);
                    const float g  = sigmoidf_(accg[i][j][r] + bgt);
                    const float xo = (float)A[(size_t)row * 512 + col];
                    const float v  = g * xo + (1.f - g) * nl;
                    if (x16out) {
                        x16out[(size_t)row * 512 + col] = (_Float16)v;
                    } else {
                        outlast[(size_t)row * 1024 + col] = v;
                        outall[(size_t)row * 1024 + col] = v;
                    }
                }
            }
        }
    }
}

// =================== persistent mega kernel (software grid barrier) ==========
__global__ void __launch_bounds__(256, 2) mega(Args a) {
    __shared__ _Float16 S[8192];   // 16 KB, carved per phase
    const int pb  = blockIdx.x;
    const int tid = threadIdx.x;

    prep_phase(a, pb, tid);
    gsync(a.bar, tid);
    qkv_phase(a, pb, tid, S, S + 4096);
    gsync(a.bar, tid);
    attn_phase(a, pb, tid);
    gsync(a.bar, tid);
    wo_phase(a, pb, tid, S, S + 2048);
    gsync(a.bar, tid);
    hw_phase(a, pb, tid, S, S + 4096, S + 6144,
             a.x16a, a.lhw16, a.rhw16, a.lhw_b, a.rhw_b,
             a.x16b, nullptr, nullptr);
    gsync(a.bar, tid);
    hw_phase(a, pb, tid, S, S + 4096, S + 6144,
             a.x16b, a.lhw16 + 524288, a.rhw16 + 524288,
             a.lhw_b + 1024, a.rhw_b + 1024,
             nullptr, a.out_last, a.out_all);
}

extern "C" void kernel_launch(void* const* d_in, const int* in_sizes, int n_in,
                              void* d_out, int out_size, void* d_ws, size_t ws_size,
                              hipStream_t stream) {
    float* out = (float*)d_out;
    _Float16* h = (_Float16*)d_ws;

    Args a;
    a.inputs    = (const float*)d_in[0];
    a.left_pad  = (const float*)d_in[1];
    a.right_pad = (const float*)d_in[2];
    a.l_Wqkv = (const float*)d_in[3];
    a.l_bqkv = (const float*)d_in[4];
    a.l_Wo   = (const float*)d_in[5];
    a.l_bo   = (const float*)d_in[6];
    a.r_Wqkv = (const float*)d_in[7];
    a.r_bqkv = (const float*)d_in[8];
    a.r_Wo   = (const float*)d_in[9];
    a.r_bo   = (const float*)d_in[10];
    a.lhw_W  = (const float*)d_in[11];
    a.lhw_b  = (const float*)d_in[12];
    a.rhw_W  = (const float*)d_in[13];
    a.rhw_b  = (const float*)d_in[14];

    a.padX16 = h;                    // 2,228,224 f16
    a.w16    = h + 2228224;          // 4,194,304 f16
    a.lqkv16 = a.w16;
    a.rqkv16 = a.w16 + 786432;
    a.lWo16  = a.w16 + 1572864;
    a.rWo16  = a.w16 + 1835008;
    a.lhw16  = a.w16 + 2097152;
    a.rhw16  = a.w16 + 3145728;
    a.qkv16  = h + 6422528;          // 13,369,344 (2 dirs)
    a.att16  = h + 19791872;         // 4,456,448  (2 dirs)
    a.x16a   = h + 24248320;         // 4,194,304  (2 dirs)
    a.x16b   = h + 28442624;         // 4,194,304  (2 dirs)
    a.out_all  = out;                // all_layers [1,B,S,2D]
    a.out_last = out + OUTHALF;      // last       [B,S,2D]

    // barrier state at the aligned tail of the workspace
    a.bar = (int*)((char*)d_ws + ((ws_size - 64) & ~(size_t)63));

    hipMemsetAsync(a.bar, 0, 8, stream);
    mega<<<dim3(NBLK), dim3(256), 0, stream>>>(a);
}